// Round 1
// baseline (1032.532 us; speedup 1.0000x reference)
//
#include <hip/hip_runtime.h>

// GraphAttn: B=8,N=1024,C=64,F=32,O=128,D=O*F=4096, M=B*N=8192 rows.
// Key identity: a[b,i,j]=leaky(a1_i+a2_j) is rank-1 pre-nonlinearity, so
// softmax(dim=i) + einsum collapses to sorted prefix/suffix sums (O(N*D)
// instead of O(N^2*D)), and h2 is never materialized (only a2 = n . W2eff).

#define ALPHA 0.2f
constexpr int Bb = 8, Nn = 1024, Cc = 64, Ff = 32, Oo = 128, Dd = 4096, Mm = 8192;
constexpr int XROW = Cc * Ff;      // 2048 floats per input row
constexpr int XPAD = XROW + 4;     // padded LDS row stride (bank spread)

// ---------------- prep: transpose w, build W2eff + const2 ----------------
__global__ __launch_bounds__(1024) void prep_kernel(
    const float* __restrict__ w, const float* __restrict__ bias,
    const float* __restrict__ att2w,
    float* __restrict__ wT, float* __restrict__ W2, float* __restrict__ c2) {
  const int tid = threadIdx.x;
  // wT[(c*3+k)*128 + o] = w[o*192 + c*3 + k]
  for (int i = tid; i < Oo * Cc * 3; i += 1024) {
    int o = i / (Cc * 3);
    int rem = i - o * (Cc * 3);
    wT[rem * Oo + o] = w[i];
  }
  // W2eff[c*32+g] = sum_{o,k} w[o,c,k] * att2w[o*32 + ((g-k+1) mod 32)]
  for (int e = tid; e < Cc * Ff; e += 1024) {
    int c = e >> 5, g = e & 31;
    float s = 0.f;
    for (int o = 0; o < Oo; ++o) {
      const float* wp = w + o * (Cc * 3) + c * 3;
      const float* ap = att2w + o * Ff;
#pragma unroll
      for (int k = 0; k < 3; ++k) s += wp[k] * ap[(g - k + 1 + Ff) & (Ff - 1)];
    }
    W2[e] = s;
  }
  // const2 = sum_o bias[o] * sum_f att2w[o*32+f]
  __shared__ float red[128];
  if (tid < 128) {
    float s = 0.f;
    for (int f = 0; f < Ff; ++f) s += att2w[tid * Ff + f];
    red[tid] = s * bias[tid];
  }
  __syncthreads();
  if (tid == 0) {
    float s = 0.f;
    for (int i = 0; i < 128; ++i) s += red[i];
    c2[0] = s;
  }
}

// ---------------- conv (h1) + a1 ----------------
// block=256 (4 waves), 8 rows/block. lane: fg=lane&7 -> f0=4*fg ; r=lane>>3.
// wave wv handles o in [wv*32, wv*32+32) as 4 chunks of 8. w via uniform
// scalar loads from wT; x from padded LDS; 96 FMA per (c,chunk) per lane.
__global__ __launch_bounds__(256) void conv_kernel(
    const float* __restrict__ x, const float* __restrict__ wT,
    const float* __restrict__ bias, const float* __restrict__ att1w,
    float* __restrict__ h1, float* __restrict__ a1) {
  __shared__ float xs[8 * XPAD];
  __shared__ float a1red[4][8];
  const int tid = threadIdx.x;
  const int lane = tid & 63;
  const int wv = tid >> 6;
  const int fg = lane & 7, r = lane >> 3;
  const int f0 = fg * 4;
  const int m0 = blockIdx.x * 8;
  const float* xbase = x + (size_t)m0 * XROW;

  // stage 8 rows (2048 floats each) into padded LDS rows
  for (int i = tid; i < 8 * 512; i += 256) {  // float4 granules
    int rr = i >> 9;
    int e = i & 511;
    float4 v = *reinterpret_cast<const float4*>(xbase + rr * XROW + e * 4);
    *reinterpret_cast<float4*>(&xs[rr * XPAD + e * 4]) = v;
  }
  __syncthreads();

  const float* xr = xs + r * XPAD;
  float a1p = 0.f;
#pragma unroll
  for (int oc = 0; oc < 4; ++oc) {
    const int o0 = wv * 32 + oc * 8;
    const int o0u = __builtin_amdgcn_readfirstlane(o0);
    float acc[8][4];
#pragma unroll
    for (int oo = 0; oo < 8; ++oo) {
      float bv = bias[o0u + oo];
      acc[oo][0] = bv; acc[oo][1] = bv; acc[oo][2] = bv; acc[oo][3] = bv;
    }
    for (int c = 0; c < Cc; ++c) {
      float xm = xr[c * 32 + ((f0 + 31) & 31)];
      float4 xc = *reinterpret_cast<const float4*>(xr + c * 32 + f0);
      float xp = xr[c * 32 + ((f0 + 4) & 31)];
      const float* wp = wT + (c * 3) * Oo + o0u;
#pragma unroll
      for (int oo = 0; oo < 8; ++oo) {
        float w0 = wp[oo], w1 = wp[Oo + oo], w2 = wp[2 * Oo + oo];
        acc[oo][0] += w0 * xm   + w1 * xc.x + w2 * xc.y;
        acc[oo][1] += w0 * xc.x + w1 * xc.y + w2 * xc.z;
        acc[oo][2] += w0 * xc.y + w1 * xc.z + w2 * xc.w;
        acc[oo][3] += w0 * xc.z + w1 * xc.w + w2 * xp;
      }
    }
    const int m = m0 + r;
#pragma unroll
    for (int oo = 0; oo < 8; ++oo) {
      float4 hv = make_float4(acc[oo][0], acc[oo][1], acc[oo][2], acc[oo][3]);
      *reinterpret_cast<float4*>(h1 + (size_t)m * Dd + (o0 + oo) * 32 + f0) = hv;
      float4 aw = *reinterpret_cast<const float4*>(att1w + (o0 + oo) * 32 + f0);
      a1p += aw.x * acc[oo][0] + aw.y * acc[oo][1] + aw.z * acc[oo][2] + aw.w * acc[oo][3];
    }
  }
  // reduce a1 partial over the 8 lanes sharing r (consecutive lanes)
  a1p += __shfl_xor(a1p, 1);
  a1p += __shfl_xor(a1p, 2);
  a1p += __shfl_xor(a1p, 4);
  if (fg == 0) a1red[wv][r] = a1p;
  __syncthreads();
  if (tid < 8) a1[m0 + tid] = a1red[0][tid] + a1red[1][tid] + a1red[2][tid] + a1red[3][tid];
}

// ---------------- a2 = n . W2eff + const2 ----------------
__global__ __launch_bounds__(256) void a2_kernel(
    const float* __restrict__ n, const float* __restrict__ W2,
    const float* __restrict__ c2, float* __restrict__ a2) {
  const int tid = threadIdx.x, lane = tid & 63, wv = tid >> 6;
  const int gw = blockIdx.x * 4 + wv;  // 4096 waves, 2 rows each
  float4 w2r[8];
#pragma unroll
  for (int q = 0; q < 8; ++q) w2r[q] = *reinterpret_cast<const float4*>(W2 + q * 256 + lane * 4);
  const float cc = c2[0];
#pragma unroll
  for (int rr = 0; rr < 2; ++rr) {
    int m = gw * 2 + rr;
    const float* np = n + (size_t)m * XROW;
    float s = 0.f;
#pragma unroll
    for (int q = 0; q < 8; ++q) {
      float4 nv = *reinterpret_cast<const float4*>(np + q * 256 + lane * 4);
      s += w2r[q].x * nv.x + w2r[q].y * nv.y + w2r[q].z * nv.z + w2r[q].w * nv.w;
    }
    s += __shfl_xor(s, 1);  s += __shfl_xor(s, 2);  s += __shfl_xor(s, 4);
    s += __shfl_xor(s, 8);  s += __shfl_xor(s, 16); s += __shfl_xor(s, 32);
    if (lane == 0) a2[m] = s + cc;
  }
}

// ---------------- per-batch sort + softmax factor prep ----------------
__global__ __launch_bounds__(1024) void sortprep_kernel(
    const float* __restrict__ a1, const float* __restrict__ a2,
    float* __restrict__ jsu, float* __restrict__ jsv, int* __restrict__ jrow,
    float* __restrict__ uorig, int* __restrict__ isrow, int* __restrict__ isk,
    float* __restrict__ isep, float* __restrict__ isea) {
  __shared__ float k1[1024]; __shared__ int x1[1024];
  __shared__ float k2[1024]; __shared__ int x2[1024];
  __shared__ float p1[1024]; __shared__ float q1[1024];
  const int tid = threadIdx.x;
  const int b = blockIdx.x;
  k1[tid] = a1[b * 1024 + tid]; x1[tid] = tid;
  k2[tid] = a2[b * 1024 + tid]; x2[tid] = tid;
  __syncthreads();
  // bitonic sort both ascending (with original indices)
  for (int k = 2; k <= 1024; k <<= 1) {
    for (int j = k >> 1; j > 0; j >>= 1) {
      int ixj = tid ^ j;
      if (ixj > tid) {
        bool up = ((tid & k) == 0);
        float va = k1[tid], vb = k1[ixj];
        if ((va > vb) == up) {
          k1[tid] = vb; k1[ixj] = va;
          int t = x1[tid]; x1[tid] = x1[ixj]; x1[ixj] = t;
        }
        float wa = k2[tid], wb = k2[ixj];
        if ((wa > wb) == up) {
          k2[tid] = wb; k2[ixj] = wa;
          int t = x2[tid]; x2[tid] = x2[ixj]; x2[ixj] = t;
        }
      }
      __syncthreads();
    }
  }
  // inclusive scans of exp(a1sorted), exp(alpha*a1sorted)
  p1[tid] = expf(k1[tid]);
  q1[tid] = expf(ALPHA * k1[tid]);
  __syncthreads();
  for (int off = 1; off < 1024; off <<= 1) {
    float ap = (tid >= off) ? p1[tid - off] : 0.f;
    float aq = (tid >= off) ? q1[tid - off] : 0.f;
    __syncthreads();
    p1[tid] += ap; q1[tid] += aq;
    __syncthreads();
  }
  const float Ptot = p1[1023];
  // j-side: u,v in a2-ascending order; also u by original index
  {
    float a2v = k2[tid];
    float thr = -a2v;
    int lo = 0, hi = 1024;
    while (lo < hi) { int mid = (lo + hi) >> 1; if (k1[mid] < thr) lo = mid + 1; else hi = mid; }
    float Psuf = Ptot - (lo ? p1[lo - 1] : 0.f);
    float Qpre = lo ? q1[lo - 1] : 0.f;
    float eb = expf(a2v), ea = expf(ALPHA * a2v);
    float den = eb * Psuf + ea * Qpre;  // softmax denominator for column j
    float u = eb / den, v = ea / den;
    jsu[b * 1024 + tid] = u;
    jsv[b * 1024 + tid] = v;
    jrow[b * 1024 + tid] = b * 1024 + x2[tid];
    uorig[b * 1024 + x2[tid]] = u;
  }
  // i-side: emission order = a1 descending (k_i non-decreasing)
  {
    float a1v = k1[tid];
    float thr = -a1v;
    int lo = 0, hi = 1024;
    while (lo < hi) { int mid = (lo + hi) >> 1; if (k2[mid] < thr) lo = mid + 1; else hi = mid; }
    int s = 1023 - tid;
    isrow[b * 1024 + s] = b * 1024 + x1[tid];
    isk[b * 1024 + s] = lo;
    isep[b * 1024 + s] = expf(a1v);
    isea[b * 1024 + s] = expf(ALPHA * a1v);
  }
}

// ---------------- U_tot partials: sum_j u_j * h1[j,:] ----------------
__global__ __launch_bounds__(512) void utot_kernel(
    const float* __restrict__ h1, const float* __restrict__ uorig,
    float* __restrict__ upart) {
  const int b = blockIdx.x >> 5;
  const int rem = blockIdx.x & 31;
  const int seg = rem >> 3, dch = rem & 7;
  const int col = dch * 512 + threadIdx.x;
  __shared__ float uo[256];
  if (threadIdx.x < 256) uo[threadIdx.x] = uorig[b * 1024 + seg * 256 + threadIdx.x];
  __syncthreads();
  const float* hp = h1 + ((size_t)(b * 1024 + seg * 256)) * Dd + col;
  float s = 0.f;
#pragma unroll 8
  for (int j = 0; j < 256; ++j) s += uo[j] * hp[(size_t)j * Dd];
  upart[(size_t)(b * 4 + seg) * Dd + col] = s;
}

// ---------------- merge sweep: prefix sums in sorted-j order + emit ----------------
__global__ __launch_bounds__(128) void sweep_kernel(
    const float* __restrict__ h1, const float* __restrict__ upart,
    const float* __restrict__ jsu, const float* __restrict__ jsv,
    const int* __restrict__ jrow, const int* __restrict__ isrow,
    const int* __restrict__ isk, const float* __restrict__ isep,
    const float* __restrict__ isea, float* __restrict__ out) {
  const int b = blockIdx.x >> 5, ch = blockIdx.x & 31;
  const int tid = threadIdx.x;
  const int col = ch * 128 + tid;
  __shared__ float Lju[1024], Ljv[1024], Lep[1024], Lea[1024];
  __shared__ int Ljr[1024], Lir[1024], Lik[1024];
  for (int i = tid; i < 1024; i += 128) {
    Lju[i] = jsu[b * 1024 + i]; Ljv[i] = jsv[b * 1024 + i]; Ljr[i] = jrow[b * 1024 + i];
    Lir[i] = isrow[b * 1024 + i]; Lik[i] = isk[b * 1024 + i];
    Lep[i] = isep[b * 1024 + i]; Lea[i] = isea[b * 1024 + i];
  }
  __syncthreads();
  float Utot = 0.f;
#pragma unroll
  for (int sg = 0; sg < 4; ++sg) Utot += upart[(size_t)(b * 4 + sg) * Dd + col];
  float U = 0.f, V = 0.f;
  int ip = 0;
  for (int t = 0; t < 1024; t += 16) {
    float rr[16];
#pragma unroll
    for (int q = 0; q < 16; ++q) rr[q] = h1[(size_t)Ljr[t + q] * Dd + col];
#pragma unroll
    for (int q = 0; q < 16; ++q) {
      const int cnt = t + q;
      while (ip < 1024 && Lik[ip] <= cnt) {  // emit rows whose split is here
        float o = Lep[ip] * (Utot - U) + Lea[ip] * V;
        out[(size_t)Lir[ip] * Dd + col] = o;
        ++ip;
      }
      U += Lju[cnt] * rr[q];
      V += Ljv[cnt] * rr[q];
    }
  }
  while (ip < 1024) {
    float o = Lep[ip] * (Utot - U) + Lea[ip] * V;
    out[(size_t)Lir[ip] * Dd + col] = o;
    ++ip;
  }
}

extern "C" void kernel_launch(void* const* d_in, const int* in_sizes, int n_in,
                              void* d_out, int out_size, void* d_ws, size_t ws_size,
                              hipStream_t stream) {
  const float* x     = (const float*)d_in[0];
  const float* n     = (const float*)d_in[1];
  const float* w     = (const float*)d_in[2];
  const float* bias  = (const float*)d_in[3];
  const float* att1w = (const float*)d_in[4];
  const float* att2w = (const float*)d_in[5];
  float* out = (float*)d_out;
  float* wsf = (float*)d_ws;

  size_t off = 0;
  float* h1    = wsf + off; off += (size_t)Mm * Dd;   // 128 MB
  float* wT    = wsf + off; off += Oo * Cc * 3;
  float* W2    = wsf + off; off += Cc * Ff;
  float* c2    = wsf + off; off += 64;
  float* a1    = wsf + off; off += Mm;
  float* a2    = wsf + off; off += Mm;
  float* jsu   = wsf + off; off += Mm;
  float* jsv   = wsf + off; off += Mm;
  int*   jrow  = (int*)(wsf + off); off += Mm;
  float* uorig = wsf + off; off += Mm;
  int*   isrow = (int*)(wsf + off); off += Mm;
  int*   isk   = (int*)(wsf + off); off += Mm;
  float* isep  = wsf + off; off += Mm;
  float* isea  = wsf + off; off += Mm;
  float* upart = wsf + off; off += (size_t)Bb * 4 * Dd;
  // total ~135.5 MB — assumes ws_size covers it

  prep_kernel<<<1, 1024, 0, stream>>>(w, bias, att2w, wT, W2, c2);
  conv_kernel<<<Mm / 8, 256, 0, stream>>>(x, wT, bias, att1w, h1, a1);
  a2_kernel<<<1024, 256, 0, stream>>>(n, W2, c2, a2);
  sortprep_kernel<<<Bb, 1024, 0, stream>>>(a1, a2, jsu, jsv, jrow, uorig,
                                           isrow, isk, isep, isea);
  utot_kernel<<<256, 512, 0, stream>>>(h1, uorig, upart);
  sweep_kernel<<<256, 128, 0, stream>>>(h1, upart, jsu, jsv, jrow,
                                        isrow, isk, isep, isea, out);
}

// Round 7
// 411.078 us; speedup vs baseline: 2.5118x; 2.5118x over previous
//
#include <hip/hip_runtime.h>

// GraphAttn: B=8,N=1024,C=64,F=32,O=128,D=O*F=4096, M=B*N=8192 rows.
// a[b,i,j]=leaky(a1_i+a2_j) is rank-1 pre-nonlinearity -> softmax(dim=i)+einsum
// collapses to sorted prefix/suffix sums. h2 never materialized (a2 = n.W2eff),
// a1 = x.W1eff (same identity). Conv = split-bf16 MFMA implicit GEMM writing h1
// in sorted-j order; segment sums fused into conv via atomics; final sweep is
// segment-parallel streaming.

#define ALPHA 0.2f
typedef __attribute__((ext_vector_type(8))) short short8;
typedef __attribute__((ext_vector_type(4))) float f32x4;

constexpr int Bb = 8, Nn = 1024, Cc = 64, Ff = 32, Oo = 128, Dd = 4096, Mm = 8192;

__device__ __forceinline__ unsigned short f2bf(float v) {
  unsigned int u = __float_as_uint(v);
  unsigned int r = (u + 0x7FFFu + ((u >> 16) & 1u)) >> 16;
  return (unsigned short)r;
}
__device__ __forceinline__ float bf2f(unsigned short h) {
  return __uint_as_float(((unsigned int)h) << 16);
}

// ---------------- prep: B-fragments (hi/lo bf16), W1eff, W2eff, c1, c2 -------
__global__ __launch_bounds__(256) void prep_kernel(
    const float* __restrict__ w, const float* __restrict__ bias,
    const float* __restrict__ att1w, const float* __restrict__ att2w,
    unsigned short* __restrict__ Bph, unsigned short* __restrict__ Bpl,
    float* __restrict__ W1, float* __restrict__ W2, float* __restrict__ c12) {
  const int tid = threadIdx.x;
  const int gid = blockIdx.x * 256 + tid;
  // B fragments: Bp[((kc*8+ot)*64+l)*8+j] = w_part[o=ot*16+(l&15), c, k]
  // with kn = kc*32 + ((l>>4)<<3) + j, c = kn&63, k = kn>>6.
  for (int e = gid; e < 6 * 8 * 64 * 8; e += 64 * 256) {
    int j = e & 7, l = (e >> 3) & 63, ot = (e >> 9) & 7, kc = e >> 12;
    int kn = kc * 32 + ((l >> 4) << 3) + j;
    int c = kn & 63, k = kn >> 6;
    int o = ot * 16 + (l & 15);
    float v = w[o * 192 + c * 3 + k];
    unsigned short hi = f2bf(v);
    Bph[e] = hi;
    Bpl[e] = f2bf(v - bf2f(hi));
  }
  // W1eff/W2eff: W[c*32+g] = sum_{o,k} w[o,c,k]*attw[o*32+((g-k+1)&31)]
  if (gid < 4096) {
    int which = gid >> 11;
    int e = gid & 2047;
    int c = e >> 5, g = e & 31;
    const float* aw = which ? att2w : att1w;
    float s = 0.f;
    for (int o = 0; o < 128; ++o) {
      const float* wp = w + o * 192 + c * 3;
      const float* ap = aw + o * 32;
#pragma unroll
      for (int k = 0; k < 3; ++k) s += wp[k] * ap[(g - k + 1 + 32) & 31];
    }
    (which ? W2 : W1)[e] = s;
  }
  // c1 = sum_o bias[o]*sum_f att1w[o,f]; c2 likewise with att2w
  if (blockIdx.x == 63) {
    __shared__ float red[256];
    int o = tid & 127;
    const float* aw = (tid < 128) ? att1w : att2w;
    float t = 0.f;
    for (int f = 0; f < 32; ++f) t += aw[o * 32 + f];
    red[tid] = t * bias[o];
    __syncthreads();
    for (int st = 64; st >= 1; st >>= 1) {
      if ((tid & 127) < st) red[tid] += red[tid + st];
      __syncthreads();
    }
    if (tid == 0) c12[0] = red[0];
    if (tid == 128) c12[1] = red[128];
  }
}

// ---------------- a1 = x.W1+c1, a2 = n.W2+c2; also zero segsum ----------------
__global__ __launch_bounds__(256) void a12_kernel(
    const float* __restrict__ x, const float* __restrict__ n,
    const float* __restrict__ W1, const float* __restrict__ W2,
    const float* __restrict__ c12, float* __restrict__ a1,
    float* __restrict__ a2, float* __restrict__ segsum) {
  const int tid = threadIdx.x, lane = tid & 63, wv = tid >> 6;
  const int gid = blockIdx.x * 256 + tid;
  segsum[(size_t)gid * 2] = 0.f;
  segsum[(size_t)gid * 2 + 1] = 0.f;
  float4 w1r[8], w2r[8];
#pragma unroll
  for (int q = 0; q < 8; ++q) {
    w1r[q] = *reinterpret_cast<const float4*>(W1 + q * 256 + lane * 4);
    w2r[q] = *reinterpret_cast<const float4*>(W2 + q * 256 + lane * 4);
  }
  const float c1 = c12[0], c2v = c12[1];
  const int gw = blockIdx.x * 4 + wv;
#pragma unroll
  for (int rr = 0; rr < 2; ++rr) {
    int m = gw * 2 + rr;
    const float* xp = x + (size_t)m * 2048;
    const float* np = n + (size_t)m * 2048;
    float s1 = 0.f, s2 = 0.f;
#pragma unroll
    for (int q = 0; q < 8; ++q) {
      float4 xv = *reinterpret_cast<const float4*>(xp + q * 256 + lane * 4);
      float4 nv = *reinterpret_cast<const float4*>(np + q * 256 + lane * 4);
      s1 += w1r[q].x * xv.x + w1r[q].y * xv.y + w1r[q].z * xv.z + w1r[q].w * xv.w;
      s2 += w2r[q].x * nv.x + w2r[q].y * nv.y + w2r[q].z * nv.z + w2r[q].w * nv.w;
    }
#pragma unroll
    for (int d = 1; d < 64; d <<= 1) {
      s1 += __shfl_xor(s1, d);
      s2 += __shfl_xor(s2, d);
    }
    if (lane == 0) { a1[m] = s1 + c1; a2[m] = s2 + c2v; }
  }
}

// ---------------- per-batch sort + softmax factor prep ----------------
__global__ __launch_bounds__(1024) void sortprep_kernel(
    const float* __restrict__ a1, const float* __restrict__ a2,
    float* __restrict__ jsu, float* __restrict__ jsv, int* __restrict__ jrow,
    int* __restrict__ isrow, int* __restrict__ isk,
    float* __restrict__ isep, float* __restrict__ isea) {
  __shared__ float k1[1024]; __shared__ int x1[1024];
  __shared__ float k2[1024]; __shared__ int x2[1024];
  __shared__ float p1[1024]; __shared__ float q1[1024];
  const int tid = threadIdx.x;
  const int b = blockIdx.x;
  k1[tid] = a1[b * 1024 + tid]; x1[tid] = tid;
  k2[tid] = a2[b * 1024 + tid]; x2[tid] = tid;
  __syncthreads();
  for (int k = 2; k <= 1024; k <<= 1) {
    for (int j = k >> 1; j > 0; j >>= 1) {
      int ixj = tid ^ j;
      if (ixj > tid) {
        bool up = ((tid & k) == 0);
        float va = k1[tid], vb = k1[ixj];
        if ((va > vb) == up) {
          k1[tid] = vb; k1[ixj] = va;
          int t = x1[tid]; x1[tid] = x1[ixj]; x1[ixj] = t;
        }
        float wa = k2[tid], wb = k2[ixj];
        if ((wa > wb) == up) {
          k2[tid] = wb; k2[ixj] = wa;
          int t = x2[tid]; x2[tid] = x2[ixj]; x2[ixj] = t;
        }
      }
      __syncthreads();
    }
  }
  p1[tid] = expf(k1[tid]);
  q1[tid] = expf(ALPHA * k1[tid]);
  __syncthreads();
  for (int off = 1; off < 1024; off <<= 1) {
    float ap = (tid >= off) ? p1[tid - off] : 0.f;
    float aq = (tid >= off) ? q1[tid - off] : 0.f;
    __syncthreads();
    p1[tid] += ap; q1[tid] += aq;
    __syncthreads();
  }
  const float Ptot = p1[1023];
  {
    float a2v = k2[tid];
    float thr = -a2v;
    int lo = 0, hi = 1024;
    while (lo < hi) { int mid = (lo + hi) >> 1; if (k1[mid] < thr) lo = mid + 1; else hi = mid; }
    float Psuf = Ptot - (lo ? p1[lo - 1] : 0.f);
    float Qpre = lo ? q1[lo - 1] : 0.f;
    float eb = expf(a2v), ea = expf(ALPHA * a2v);
    float den = eb * Psuf + ea * Qpre;
    jsu[b * 1024 + tid] = eb / den;
    jsv[b * 1024 + tid] = ea / den;
    jrow[b * 1024 + tid] = b * 1024 + x2[tid];
  }
  {
    float a1v = k1[tid];
    float thr = -a1v;
    int lo = 0, hi = 1024;
    while (lo < hi) { int mid = (lo + hi) >> 1; if (k2[mid] < thr) lo = mid + 1; else hi = mid; }
    int s = 1023 - tid;
    isrow[b * 1024 + s] = b * 1024 + x1[tid];
    isk[b * 1024 + s] = lo;
    isep[b * 1024 + s] = expf(a1v);
    isea[b * 1024 + s] = expf(ALPHA * a1v);
  }
}

// ---------------- conv: split-bf16 MFMA, writes h1 in sorted-j order ---------
// block = 4 waves, 16 sorted rows. Wave wv owns o in [wv*32, wv*32+32) as two
// 16-col MFMA tiles with persistent B-frags (wh/wl). Per row: x row staged to
// LDS as xh/xl in [f][c] layout with XOR-16B swizzle; 12 a-frag-pair reads feed
// 72 MFMAs (3-term split product). Segment U/V sums accumulate in registers,
// one atomicAdd per lane-slot at block end.
__global__ __launch_bounds__(256, 2) void conv_kernel(
    const float* __restrict__ x,
    const unsigned short* __restrict__ Bph, const unsigned short* __restrict__ Bpl,
    const float* __restrict__ bias,
    const int* __restrict__ jrow, const float* __restrict__ jsu,
    const float* __restrict__ jsv,
    float* __restrict__ h1s, float* __restrict__ segsum) {
  __shared__ unsigned char xsraw[16384];  // [2 buf][2 part][32 f][64 c] bf16
  const int tid = threadIdx.x, lane = tid & 63, wv = tid >> 6;
  const int s0 = blockIdx.x * 16;

  short8 bh[6][2], bl[6][2];
#pragma unroll
  for (int kc = 0; kc < 6; ++kc)
#pragma unroll
    for (int t2 = 0; t2 < 2; ++t2) {
      int ot = wv * 2 + t2;
      size_t idx = ((size_t)(kc * 8 + ot) * 64 + lane) * 8;
      bh[kc][t2] = *reinterpret_cast<const short8*>(Bph + idx);
      bl[kc][t2] = *reinterpret_cast<const short8*>(Bpl + idx);
    }
  float biasv[2];
  biasv[0] = bias[(wv * 2 + 0) * 16 + (lane & 15)];
  biasv[1] = bias[(wv * 2 + 1) * 16 + (lane & 15)];

  int offs[2][6];
#pragma unroll
  for (int ft = 0; ft < 2; ++ft)
#pragma unroll
    for (int kc = 0; kc < 6; ++kc) {
      int fo = ft * 16 + (lane & 15);
      int kb = kc * 32 + ((lane >> 4) << 3);
      int k = kb >> 6, c0 = kb & 63;
      int fx = (fo + k + 31) & 31;  // (fo + k - 1) mod 32
      int bo = (fx << 7) + (c0 << 1);
      offs[ft][kc] = bo ^ ((fx & 7) << 4);
    }

  float Uacc[2][2][4] = {{{0.f}}};
  float Vacc[2][2][4] = {{{0.f}}};
  const int cpair = tid & 31, fq = tid >> 5;

  auto stage = [&](int r, int bf) {
    int m = jrow[s0 + r];
    const float* xr = x + (size_t)m * 2048;
    int c = cpair * 2;
    float4 v0 = *reinterpret_cast<const float4*>(xr + c * 32 + fq * 4);
    float4 v1 = *reinterpret_cast<const float4*>(xr + (c + 1) * 32 + fq * 4);
    unsigned char* base = xsraw + bf * 8192;
#pragma unroll
    for (int ff = 0; ff < 4; ++ff) {
      int f = fq * 4 + ff;
      float av = (&v0.x)[ff], bv = (&v1.x)[ff];
      unsigned short ah = f2bf(av), bh_ = f2bf(bv);
      unsigned short al = f2bf(av - bf2f(ah)), bl_ = f2bf(bv - bf2f(bh_));
      int bo = ((f << 7) + (c << 1)) ^ ((f & 7) << 4);
      *reinterpret_cast<unsigned int*>(base + bo) =
          (unsigned int)ah | ((unsigned int)bh_ << 16);
      *reinterpret_cast<unsigned int*>(base + 4096 + bo) =
          (unsigned int)al | ((unsigned int)bl_ << 16);
    }
  };

  stage(0, 0);
  __syncthreads();
  for (int r = 0; r < 16; ++r) {
    if (r < 15) stage(r + 1, (r + 1) & 1);
    const unsigned char* bufb = xsraw + (r & 1) * 8192;
    f32x4 acc[2][2];
#pragma unroll
    for (int ft = 0; ft < 2; ++ft)
#pragma unroll
      for (int t2 = 0; t2 < 2; ++t2) {
        f32x4 z = {0.f, 0.f, 0.f, 0.f};
        acc[ft][t2] = z;
      }
#pragma unroll
    for (int kc = 0; kc < 6; ++kc) {
#pragma unroll
      for (int ft = 0; ft < 2; ++ft) {
        short8 ah = *reinterpret_cast<const short8*>(bufb + offs[ft][kc]);
        short8 al = *reinterpret_cast<const short8*>(bufb + 4096 + offs[ft][kc]);
        acc[ft][0] = __builtin_amdgcn_mfma_f32_16x16x32_bf16(ah, bh[kc][0], acc[ft][0], 0, 0, 0);
        acc[ft][1] = __builtin_amdgcn_mfma_f32_16x16x32_bf16(ah, bh[kc][1], acc[ft][1], 0, 0, 0);
        acc[ft][0] = __builtin_amdgcn_mfma_f32_16x16x32_bf16(ah, bl[kc][0], acc[ft][0], 0, 0, 0);
        acc[ft][1] = __builtin_amdgcn_mfma_f32_16x16x32_bf16(ah, bl[kc][1], acc[ft][1], 0, 0, 0);
        acc[ft][0] = __builtin_amdgcn_mfma_f32_16x16x32_bf16(al, bh[kc][0], acc[ft][0], 0, 0, 0);
        acc[ft][1] = __builtin_amdgcn_mfma_f32_16x16x32_bf16(al, bh[kc][1], acc[ft][1], 0, 0, 0);
      }
    }
    const int s = s0 + r;
    const float ju = jsu[s], jv = jsv[s];
    float* hrow = h1s + (size_t)s * 4096;
#pragma unroll
    for (int ft = 0; ft < 2; ++ft)
#pragma unroll
      for (int t2 = 0; t2 < 2; ++t2) {
        int f_base = ft * 16 + ((lane >> 4) << 2);
        int o_out = (wv * 2 + t2) * 16 + (lane & 15);
        float4 hv;
#pragma unroll
        for (int reg = 0; reg < 4; ++reg) {
          float val = acc[ft][t2][reg] + biasv[t2];
          (&hv.x)[reg] = val;
          Uacc[ft][t2][reg] += ju * val;
          Vacc[ft][t2][reg] += jv * val;
        }
        *reinterpret_cast<float4*>(hrow + o_out * 32 + f_base) = hv;
      }
    __syncthreads();
  }
  const int g = blockIdx.x >> 3;  // global segment (b*8+seg)
  float* su = segsum + (size_t)g * 2 * 4096;
#pragma unroll
  for (int ft = 0; ft < 2; ++ft)
#pragma unroll
    for (int t2 = 0; t2 < 2; ++t2)
#pragma unroll
      for (int reg = 0; reg < 4; ++reg) {
        int col = ((wv * 2 + t2) * 16 + (lane & 15)) * 32 + ft * 16 +
                  ((lane >> 4) << 2) + reg;
        atomicAdd(su + col, Uacc[ft][t2][reg]);
        atomicAdd(su + 4096 + col, Vacc[ft][t2][reg]);
      }
}

// ---------------- pass2: segment-parallel streaming sweep + emit -------------
__global__ __launch_bounds__(128) void pass2_kernel(
    const float* __restrict__ h1s, const float* __restrict__ segsum,
    const float* __restrict__ jsu, const float* __restrict__ jsv,
    const int* __restrict__ isrow, const int* __restrict__ isk,
    const float* __restrict__ isep, const float* __restrict__ isea,
    float* __restrict__ out) {
  const int tid = threadIdx.x;
  const int chunk = blockIdx.x & 31, gseg = blockIdx.x >> 5;
  const int b = gseg >> 3, seg = gseg & 7;
  const int col = chunk * 128 + tid;
  __shared__ int kL[1024];
  __shared__ float epL[1024];
  __shared__ float eaL[1024];
  __shared__ int rowL[1024];
  __shared__ float juL[128];
  __shared__ float jvL[128];
  for (int i = tid; i < 1024; i += 128) {
    kL[i] = isk[b * 1024 + i];
    epL[i] = isep[b * 1024 + i];
    eaL[i] = isea[b * 1024 + i];
    rowL[i] = isrow[b * 1024 + i];
  }
  juL[tid] = jsu[b * 1024 + seg * 128 + tid];
  jvL[tid] = jsv[b * 1024 + seg * 128 + tid];
  float U = 0.f, V = 0.f, Utot = 0.f;
#pragma unroll
  for (int s8 = 0; s8 < 8; ++s8) {
    float uu = segsum[((size_t)(b * 8 + s8) * 2) * 4096 + col];
    float vv = segsum[((size_t)(b * 8 + s8) * 2 + 1) * 4096 + col];
    Utot += uu;
    if (s8 < seg) { U += uu; V += vv; }
  }
  __syncthreads();
  int ip, ip1;
  {
    int lo = 0, hi = 1024, thr = seg * 128;
    while (lo < hi) { int mid = (lo + hi) >> 1; if (kL[mid] < thr) lo = mid + 1; else hi = mid; }
    ip = lo;
  }
  if (seg == 7) ip1 = 1024;
  else {
    int lo = ip, hi = 1024, thr = seg * 128 + 128;
    while (lo < hi) { int mid = (lo + hi) >> 1; if (kL[mid] < thr) lo = mid + 1; else hi = mid; }
    ip1 = lo;
  }
  const float* hrow = h1s + ((size_t)(b * 1024 + seg * 128)) * 4096 + col;
  for (int t = 0; t < 128; t += 16) {
    float rr[16];
#pragma unroll
    for (int q = 0; q < 16; ++q) rr[q] = hrow[(size_t)(t + q) * 4096];
#pragma unroll
    for (int q = 0; q < 16; ++q) {
      int cnt = seg * 128 + t + q;
      while (ip < ip1 && kL[ip] <= cnt) {
        out[(size_t)rowL[ip] * 4096 + col] = epL[ip] * (Utot - U) + eaL[ip] * V;
        ++ip;
      }
      U += juL[t + q] * rr[q];
      V += jvL[t + q] * rr[q];
    }
  }
  while (ip < ip1) {
    out[(size_t)rowL[ip] * 4096 + col] = epL[ip] * (Utot - U) + eaL[ip] * V;
    ++ip;
  }
}

extern "C" void kernel_launch(void* const* d_in, const int* in_sizes, int n_in,
                              void* d_out, int out_size, void* d_ws, size_t ws_size,
                              hipStream_t stream) {
  const float* x     = (const float*)d_in[0];
  const float* n     = (const float*)d_in[1];
  const float* w     = (const float*)d_in[2];
  const float* bias  = (const float*)d_in[3];
  const float* att1w = (const float*)d_in[4];
  const float* att2w = (const float*)d_in[5];
  float* out = (float*)d_out;
  float* wsf = (float*)d_ws;

  size_t off = 0;
  float* h1s  = wsf + off; off += (size_t)Mm * Dd;  // 128 MB, sorted-j order
  float* W1   = wsf + off; off += 2048;
  float* W2   = wsf + off; off += 2048;
  float* c12  = wsf + off; off += 64;
  float* a1v  = wsf + off; off += Mm;
  float* a2v  = wsf + off; off += Mm;
  float* jsu  = wsf + off; off += Mm;
  float* jsv  = wsf + off; off += Mm;
  int*   jrow = (int*)(wsf + off); off += Mm;
  int*   isrow= (int*)(wsf + off); off += Mm;
  int*   isk  = (int*)(wsf + off); off += Mm;
  float* isep = wsf + off; off += Mm;
  float* isea = wsf + off; off += Mm;
  float* segsum = wsf + off; off += (size_t)64 * 2 * 4096;  // 2 MB
  unsigned short* Bph = (unsigned short*)(wsf + off); off += 12288;
  unsigned short* Bpl = (unsigned short*)(wsf + off); off += 12288;
  // total ~130.4 MB

  prep_kernel<<<64, 256, 0, stream>>>(w, bias, att1w, att2w, Bph, Bpl, W1, W2, c12);
  a12_kernel<<<1024, 256, 0, stream>>>(x, n, W1, W2, c12, a1v, a2v, segsum);
  sortprep_kernel<<<Bb, 1024, 0, stream>>>(a1v, a2v, jsu, jsv, jrow,
                                           isrow, isk, isep, isea);
  conv_kernel<<<512, 256, 0, stream>>>(x, Bph, Bpl, bias, jrow, jsu, jsv,
                                       h1s, segsum);
  pass2_kernel<<<2048, 128, 0, stream>>>(h1s, segsum, jsu, jsv,
                                         isrow, isk, isep, isea, out);
}